// Round 1
// 12042.281 us; speedup vs baseline: 1.7426x; 1.7426x over previous
//
#include <hip/hip_runtime.h>
#include <stdint.h>

#define TT   4096
#define HD   1024
#define EH   2048
#define NGR  4096
#define VOC  50257

typedef __attribute__((ext_vector_type(4))) float floatx4;
typedef __attribute__((ext_vector_type(8))) short shortx8;

static __device__ __forceinline__ unsigned short f2b(float f){
  union { float f; unsigned u; } v; v.f = f;
  unsigned r = v.u + 0x7FFFu + ((v.u >> 16) & 1u);   // RNE fp32->bf16
  return (unsigned short)(r >> 16);
}

// ---------------------------------------------------------------------------
// init: hexch row 0 = (tag=1 | h=0,0)  (h_0 = 0)
// ---------------------------------------------------------------------------
__global__ void k_init(unsigned long long* __restrict__ hexch){
  hexch[threadIdx.x] = (unsigned long long)1 << 32;
}

// ---------------------------------------------------------------------------
// G1: Xproj[T, 4*H] = emb[sentence] @ Wx^T + bias   (bf16 MFMA, NT GEMM)
// tile 128x128, BK=64, 256 thr, 2x2 waves of 64x64
// ---------------------------------------------------------------------------
__global__ __launch_bounds__(256)
void g1_xproj(const int* __restrict__ sent, const float* __restrict__ emb,
              const float* __restrict__ Wf, const float* __restrict__ Wi,
              const float* __restrict__ Wg, const float* __restrict__ Wo,
              const float* __restrict__ bfp, const float* __restrict__ bip,
              const float* __restrict__ bgp, const float* __restrict__ bop,
              float* __restrict__ Xproj)
{
  __shared__ unsigned short Asl[128*64];
  __shared__ unsigned short Bsl[128*64];
  const int bid   = blockIdx.x;
  const int mbase = (bid & 31) * 128;
  const int nbase = (bid >> 5) * 128;
  const int gate  = nbase >> 10;                 // uniform per block (128 | 1024)
  const float* __restrict__ Wsel = (gate==0)?Wf:(gate==1)?Wi:(gate==2)?Wg:Wo;
  const float* __restrict__ bsel = (gate==0)?bfp:(gate==1)?bip:(gate==2)?bgp:bop;
  const int j0 = nbase & 1023;

  const int tid  = threadIdx.x;
  const int lane = tid & 63, wave = tid >> 6;
  const int wm = wave & 1, wn = wave >> 1;
  const int lr = lane & 15, quad = lane >> 4;
  const int sr = tid >> 4, sc4 = (tid & 15) * 4;

  floatx4 acc[4][4];
#pragma unroll
  for (int m=0;m<4;m++)
#pragma unroll
    for (int n=0;n<4;n++){ floatx4 z = {0.f,0.f,0.f,0.f}; acc[m][n]=z; }

  for (int kb = 0; kb < 1024; kb += 64){
#pragma unroll
    for (int it=0; it<8; ++it){
      const int rr = it*16 + sr;
      const int s  = sent[mbase + rr];
      float4 av = *(const float4*)&emb[(size_t)s*HD + kb + sc4];
      ushort4 ua; ua.x=f2b(av.x); ua.y=f2b(av.y); ua.z=f2b(av.z); ua.w=f2b(av.w);
      *(ushort4*)&Asl[rr*64 + sc4] = ua;
      float4 bv = *(const float4*)&Wsel[(size_t)(j0+rr)*EH + kb + sc4];
      ushort4 ub; ub.x=f2b(bv.x); ub.y=f2b(bv.y); ub.z=f2b(bv.z); ub.w=f2b(bv.w);
      *(ushort4*)&Bsl[rr*64 + sc4] = ub;
    }
    __syncthreads();
#pragma unroll
    for (int kk=0; kk<2; ++kk){
      shortx8 af[4], bfv[4];
#pragma unroll
      for (int m=0;m<4;m++) af[m]  = *(const shortx8*)&Asl[(wm*64+m*16+lr)*64 + kk*32 + quad*8];
#pragma unroll
      for (int n=0;n<4;n++) bfv[n] = *(const shortx8*)&Bsl[(wn*64+n*16+lr)*64 + kk*32 + quad*8];
#pragma unroll
      for (int m=0;m<4;m++)
#pragma unroll
        for (int n=0;n<4;n++)
          acc[m][n] = __builtin_amdgcn_mfma_f32_16x16x32_bf16(af[m], bfv[n], acc[m][n], 0,0,0);
    }
    __syncthreads();
  }

#pragma unroll
  for (int m=0;m<4;m++){
    const int row = mbase + wm*64 + m*16 + quad*4;
#pragma unroll
    for (int n=0;n<4;n++){
      const int cl   = wn*64 + n*16 + lr;
      const float bs = bsel[j0 + cl];
      const int col  = nbase + cl;
#pragma unroll
      for (int r2=0;r2<4;r2++)
        Xproj[(size_t)(row+r2)*NGR + col] = acc[m][n][r2] + bs;
    }
  }
}

// ---------------------------------------------------------------------------
// REC: 128 persistent WGs x 512 thr (4x more CUs than before; per-CU LDS-pipe
// load for the h-MAC drops 4096cy -> 1024cy). Wh register-resident as packed
// bf16 (32 dwords/thread covering 64 cols). h exchanged via tagged 64-bit
// relaxed agent-scope atomics (identical protocol/numerics to prior version).
//
// Thread map: sub = tid&15 (col-chunk of 64), p = tid>>4 (0..31),
//             gate = p>>3, jl = p&7, row j = w*8 + jl.
// LDS h layout: [16][68] f32 (stride 68 -> 16B-aligned float4 reads,
//             bank = (4*sub + k) % 32 -> worst 2-way aliasing = free).
// ---------------------------------------------------------------------------
__global__ __launch_bounds__(512)
void lstm_rec(const float* __restrict__ Wf, const float* __restrict__ Wi,
              const float* __restrict__ Wg, const float* __restrict__ Wo,
              const float* __restrict__ Xproj,
              float* __restrict__ hseq,
              unsigned long long* __restrict__ hexch)
{
  __shared__ float lds_h[16*68];
  __shared__ float zbuf[32];

  const int w   = blockIdx.x;        // 0..127
  const int tid = threadIdx.x;       // 0..511
  const int sub = tid & 15;          // 64-col chunk
  const int p   = tid >> 4;          // 0..31 (gate,row) pair
  const int gate= p >> 3;            // 0..3
  const int jl  = p & 7;             // 0..7
  const int j   = w*8 + jl;          // global row

  const float* __restrict__ Wsel = (gate==0)?Wf:(gate==1)?Wi:(gate==2)?Wg:Wo;
  const float* __restrict__ wrow = Wsel + (size_t)j*EH + HD + sub*64;

  unsigned wq[32];
#pragma unroll
  for (int k2=0; k2<16; ++k2){
    float4 v = *(const float4*)(wrow + 4*k2);
    wq[2*k2]   = (unsigned)f2b(v.x) | ((unsigned)f2b(v.y)<<16);
    wq[2*k2+1] = (unsigned)f2b(v.z) | ((unsigned)f2b(v.w)<<16);
  }

  float c = 0.f;
  const float* hl = lds_h + sub*68;

  // xp for step 0; subsequent steps are prefetched one step ahead so the
  // load's L3 latency hides under the MAC instead of the B1->activation path
  float xp = 0.f;
  if (sub == 0) xp = Xproj[(size_t)0*NGR + gate*HD + j];

  for (int step=0; step<TT; ++step){
    // --- acquire h_{step}: every thread polls one tagged word, drops 2 f32 into LDS
    {
      const size_t base = (size_t)step*512 + tid;
      const unsigned long long expect = (unsigned long long)(step+1);
      unsigned long long word =
        __hip_atomic_load(&hexch[base], __ATOMIC_RELAXED, __HIP_MEMORY_SCOPE_AGENT);
      while ((word >> 32) != expect){
        __builtin_amdgcn_s_sleep(1);
        word = __hip_atomic_load(&hexch[base], __ATOMIC_RELAXED, __HIP_MEMORY_SCOPE_AGENT);
      }
      const unsigned lo = (unsigned)word;
      const int fs = tid >> 5, fm = tid & 31;       // cols (2*tid, 2*tid+1)
      float* dst = &lds_h[fs*68 + 2*fm];
      dst[0] = __uint_as_float(lo << 16);
      dst[1] = __uint_as_float(lo & 0xffff0000u);
    }
    __syncthreads();                                   // B1

    float xp_next = 0.f;
    if (sub == 0 && step+1 < TT)
      xp_next = Xproj[(size_t)(step+1)*NGR + gate*HD + j];

    // --- MAC: 64 cols per thread, float4 LDS reads, packed-bf16 weights ---
    float a0 = 0.f, a1 = 0.f;
#pragma unroll
    for (int q=0;q<16;q++){
      const unsigned u0 = wq[2*q], u1 = wq[2*q+1];
      const float4 h4 = *(const float4*)(hl + 4*q);
      a0 = fmaf(__uint_as_float(u0 << 16),          h4.x, a0);
      a1 = fmaf(__uint_as_float(u0 & 0xffff0000u),  h4.y, a1);
      a0 = fmaf(__uint_as_float(u1 << 16),          h4.z, a0);
      a1 = fmaf(__uint_as_float(u1 & 0xffff0000u),  h4.w, a1);
    }
    float acc = a0 + a1;
    acc += __shfl_xor(acc, 1);
    acc += __shfl_xor(acc, 2);
    acc += __shfl_xor(acc, 4);
    acc += __shfl_xor(acc, 8);

    if (sub == 0){
      const float z = acc + xp;
      float v;
      if (gate == 2){ const float e = __expf(2.f*z); v = (e-1.f)/(e+1.f); }  // tanh
      else          { v = 1.f/(1.f + __expf(-z)); }                           // sigmoid
      zbuf[p] = v;
    }
    __syncthreads();                                   // B2

    if (tid < 8){
      const float f = zbuf[tid],     i = zbuf[8+tid];
      const float g = zbuf[16+tid],  o = zbuf[24+tid];
      c = fmaf(f, c, i*g);
      const float e  = __expf(2.f*c);
      const float th = (e-1.f)/(e+1.f);
      const float hn = o*th;
      hseq[(size_t)(step+1)*HD + w*8 + tid] = hn;      // lstm_out (fp32, plain)
      const float hp2 = __shfl_xor(hn, 1);
      if ((tid & 1) == 0){
        const unsigned lo = (unsigned)f2b(hn) | ((unsigned)f2b(hp2) << 16);
        const unsigned long long wordo = ((unsigned long long)(step+2) << 32) | lo;
        __hip_atomic_store(&hexch[(size_t)(step+1)*512 + w*4 + (tid>>1)], wordo,
                           __ATOMIC_RELAXED, __HIP_MEMORY_SCOPE_AGENT);
      }
    }
    xp = xp_next;
  }
}

// ---------------------------------------------------------------------------
// G3: logits[T, VOC] = hseq[1:] @ Wt^T + bt  (bf16 MFMA; A/B converted in staging)
// ---------------------------------------------------------------------------
__global__ __launch_bounds__(256)
void g3_logits(const float* __restrict__ hseq1, const float* __restrict__ Wt,
               const float* __restrict__ bt, float* __restrict__ out)
{
  __shared__ unsigned short Asl[128*64];
  __shared__ unsigned short Bsl[128*64];
  const int bid   = blockIdx.x;
  const int mbase = (bid & 31) * 128;       // row tile fastest: share Wt panel in L2
  const int nbase = (bid >> 5) * 128;

  const int tid  = threadIdx.x;
  const int lane = tid & 63, wave = tid >> 6;
  const int wm = wave & 1, wn = wave >> 1;
  const int lr = lane & 15, quad = lane >> 4;
  const int sr = tid >> 4, sc4 = (tid & 15) * 4;

  floatx4 acc[4][4];
#pragma unroll
  for (int m=0;m<4;m++)
#pragma unroll
    for (int n=0;n<4;n++){ floatx4 z = {0.f,0.f,0.f,0.f}; acc[m][n]=z; }

  for (int kb = 0; kb < 1024; kb += 64){
#pragma unroll
    for (int it=0; it<8; ++it){
      const int rr = it*16 + sr;
      float4 av = *(const float4*)&hseq1[(size_t)(mbase+rr)*HD + kb + sc4];
      ushort4 ua; ua.x=f2b(av.x); ua.y=f2b(av.y); ua.z=f2b(av.z); ua.w=f2b(av.w);
      *(ushort4*)&Asl[rr*64 + sc4] = ua;
      const int gn = nbase + rr;
      float4 bv = {0.f,0.f,0.f,0.f};
      if (gn < VOC) bv = *(const float4*)&Wt[(size_t)gn*HD + kb + sc4];
      ushort4 ub; ub.x=f2b(bv.x); ub.y=f2b(bv.y); ub.z=f2b(bv.z); ub.w=f2b(bv.w);
      *(ushort4*)&Bsl[rr*64 + sc4] = ub;
    }
    __syncthreads();
#pragma unroll
    for (int kk=0; kk<2; ++kk){
      shortx8 af[4], bfv[4];
#pragma unroll
      for (int m=0;m<4;m++) af[m]  = *(const shortx8*)&Asl[(wm*64+m*16+lr)*64 + kk*32 + quad*8];
#pragma unroll
      for (int n=0;n<4;n++) bfv[n] = *(const shortx8*)&Bsl[(wn*64+n*16+lr)*64 + kk*32 + quad*8];
#pragma unroll
      for (int m=0;m<4;m++)
#pragma unroll
        for (int n=0;n<4;n++)
          acc[m][n] = __builtin_amdgcn_mfma_f32_16x16x32_bf16(af[m], bfv[n], acc[m][n], 0,0,0);
    }
    __syncthreads();
  }

#pragma unroll
  for (int m=0;m<4;m++){
    const int row = mbase + wm*64 + m*16 + quad*4;
#pragma unroll
    for (int n=0;n<4;n++){
      const int col = nbase + wn*64 + n*16 + lr;
      if (col < VOC){
        const float bs = bt[col];
#pragma unroll
        for (int r2=0;r2<4;r2++)
          out[(size_t)(row+r2)*VOC + col] = acc[m][n][r2] + bs;
      }
    }
  }
}

// ---------------------------------------------------------------------------
// K5: per-row online logsumexp over VOC
// ---------------------------------------------------------------------------
__global__ __launch_bounds__(256)
void k_lse(const float* __restrict__ out, float* __restrict__ lse){
  const int row = blockIdx.x, tid = threadIdx.x;
  const float* p = out + (size_t)row*VOC;
  float m = -1e30f, s = 0.f;
  for (int cc = tid; cc < VOC; cc += 256){
    const float v = p[cc];
    if (v > m){ s = s*__expf(m - v) + 1.f; m = v; }
    else      { s += __expf(v - m); }
  }
#pragma unroll
  for (int off=1; off<64; off<<=1){
    const float mo = __shfl_xor(m, off), so = __shfl_xor(s, off);
    const float M = fmaxf(m, mo);
    s = s*__expf(m - M) + so*__expf(mo - M);
    m = M;
  }
  __shared__ float ms[4], ss[4];
  if ((tid & 63) == 0){ ms[tid>>6] = m; ss[tid>>6] = s; }
  __syncthreads();
  if (tid == 0){
    float M = ms[0], S = ss[0];
    for (int i=1;i<4;i++){
      const float mo = ms[i], so = ss[i];
      const float MM = fmaxf(M, mo);
      S = S*__expf(M - MM) + so*__expf(mo - MM);
      M = MM;
    }
    lse[row] = M + __logf(S);
  }
}

// ---------------------------------------------------------------------------
// K6: out -= lse[row]
// ---------------------------------------------------------------------------
__global__ __launch_bounds__(256)
void k_sub(float* __restrict__ out, const float* __restrict__ lse){
  const int row = blockIdx.y;
  const int col = blockIdx.x*256 + threadIdx.x;
  if (col < VOC) out[(size_t)row*VOC + col] -= lse[row];
}

// ---------------------------------------------------------------------------
extern "C" void kernel_launch(void* const* d_in, const int* in_sizes, int n_in,
                              void* d_out, int out_size, void* d_ws, size_t ws_size,
                              hipStream_t stream)
{
  const int*   sent = (const int*)  d_in[0];
  const float* emb  = (const float*)d_in[1];
  const float* Wf   = (const float*)d_in[2];
  const float* bfp  = (const float*)d_in[3];
  const float* Wi   = (const float*)d_in[4];
  const float* bip  = (const float*)d_in[5];
  const float* Wg   = (const float*)d_in[6];
  const float* bgp  = (const float*)d_in[7];
  const float* Wo   = (const float*)d_in[8];
  const float* bop  = (const float*)d_in[9];
  const float* Wt   = (const float*)d_in[10];
  const float* bt   = (const float*)d_in[11];
  float* out = (float*)d_out;

  char* ws = (char*)d_ws;
  size_t off = 0;
  float* Xproj = (float*)(ws + off);              off += (size_t)TT*NGR*4;      // 64 MiB
  float* hseq  = (float*)(ws + off);              off += (size_t)(TT+1)*HD*4;   // 16 MiB
  unsigned long long* hexch = (unsigned long long*)(ws + off);
                                                  off += (size_t)(TT+1)*512*8;  // 16 MiB
  float* lse   = (float*)(ws + off);              off += (size_t)TT*4;

  k_init<<<1, 512, 0, stream>>>(hexch);
  g1_xproj<<<1024, 256, 0, stream>>>(sent, emb, Wf, Wi, Wg, Wo, bfp, bip, bgp, bop, Xproj);
  lstm_rec<<<128, 512, 0, stream>>>(Wf, Wi, Wg, Wo, Xproj, hseq, hexch);
  g3_logits<<<32*393, 256, 0, stream>>>(hseq + HD, Wt, bt, out);
  k_lse<<<TT, 256, 0, stream>>>(out, lse);
  dim3 g6(197, TT);
  k_sub<<<g6, 256, 0, stream>>>(out, lse);
}